// Round 7
// baseline (2426.974 us; speedup 1.0000x reference)
//
#include <hip/hip_runtime.h>
#include <math.h>

// Problem constants (B=16, T=2000, E=1024, K=2048)
#define N_ROWS 32000
#define DIM    1024
#define NCENT  2048
#define MROWS  64            // x rows per block
#define NKP    256           // centroids per k-pass
#define KE     32            // e per staged chunk
#define NPASS  (NCENT / NKP) // 8
#define NCHUNK (DIM / KE)    // 32
#define GTOT   (NPASS * NCHUNK) // 256 flattened chunks
#define TAU    0.3f          // rescore margin (~13 sigma of single-f16 dot error)
#define CS_KK  257           // 256 + 1 pad
#define XS_KK  65            // 64 + 1 pad

typedef _Float16 half4v __attribute__((ext_vector_type(4)));
typedef _Float16 half8v __attribute__((ext_vector_type(8)));
typedef float    floatx16 __attribute__((ext_vector_type(16)));

// float4 -> f16x4 (RNE scalar casts; pkrtz's return type clashes with our
// vector typedef and RNE is fine numerically).
__device__ __forceinline__ half4v cvt4_f16(const float4 v) {
  half4v h;
  h[0] = (_Float16)v.x; h[1] = (_Float16)v.y;
  h[2] = (_Float16)v.z; h[3] = (_Float16)v.w;
  return h;
}

// ---------- Kernel A: C fp32 -> f16 + exact fp32 norms, once ----------
__global__ void __launch_bounds__(256) convert_c_kernel(
    const float* __restrict__ cent, _Float16* __restrict__ cf16,
    float* __restrict__ nrm) {
  const int k = blockIdx.x;
  const int t = threadIdx.x;
  const float4 v = ((const float4*)(cent + (size_t)k * DIM))[t];
  float n = v.x * v.x + v.y * v.y + v.z * v.z + v.w * v.w;
  *(half4v*)(cf16 + (size_t)k * DIM + 4 * t) = cvt4_f16(v);
  __shared__ float red[4];
#pragma unroll
  for (int off = 32; off > 0; off >>= 1) n += __shfl_down(n, off, 64);
  if ((t & 63) == 0) red[t >> 6] = n;
  __syncthreads();
  if (t == 0) nrm[k] = red[0] + red[1] + red[2] + red[3];
}

// ---------- Kernel B: f16 MFMA sweep + fp32 rescue ----------
// Block = 256 thr = 4 waves; wave w owns k-quarter (64 k) of each 256-k pass.
// Double-buffered LDS chunks (KE=32 e), 1 barrier per chunk; chunk g+1 is
// prefetched to registers before chunk g's MFMA, converted/written after.
// mfma_f32_32x32x16_f16: A[m=lane&31][e=(lane>>5)*8+j], B[e][n=lane&31],
// D: col=lane&31, row=(reg&3)+8*(reg>>2)+4*(lane>>5)   [validated in R5].
__global__ void __launch_bounds__(256, 2) kmeans_mfma_f16(
    const float* __restrict__ x, const _Float16* __restrict__ cf16,
    const float* __restrict__ nrm_g, const float* __restrict__ cent,
    int* __restrict__ out) {
  __shared__ __align__(16) _Float16 csh[2][4][CS_KK][8];  // 32,896 B
  __shared__ __align__(16) _Float16 xsh[2][4][XS_KK][8];  //  8,320 B
  __shared__ float snrm[NKP];
  __shared__ float sbest[MROWS][4];
  __shared__ float sbest2[MROWS][4];
  __shared__ int   sbidx[MROWS][4];
  __shared__ int   sres[MROWS];
  __shared__ int   sflag[MROWS];
  __shared__ float p2d[4];
  __shared__ int   p2k[4];

  const int t    = threadIdx.x;
  const int lane = t & 63;
  const int w    = t >> 6;
  const int l31  = lane & 31;
  const int lhi  = lane >> 5;
  const size_t row0 = (size_t)blockIdx.x * MROWS;

  float best[2]  = {INFINITY, INFINITY};
  float best2[2] = {INFINITY, INFINITY};
  int   bidx[2]  = {0, 0};
  floatx16 acc[2][2];

  uint4  cpre[4];
  float4 xpre[2];

  // Prologue: load + convert + write chunk 0 into buf 0.
  {
#pragma unroll
    for (int i = 0; i < 4; ++i) {
      const int idx = t + 256 * i, kk = idx >> 2, esub = idx & 3;
      cpre[i] = *(const uint4*)(cf16 + (size_t)kk * DIM + esub * 8);
    }
#pragma unroll
    for (int i = 0; i < 2; ++i) {
      const int idx = t + 256 * i, row = idx >> 3, e4 = idx & 7;
      xpre[i] = *(const float4*)(x + (row0 + row) * DIM + 4 * e4);
    }
#pragma unroll
    for (int i = 0; i < 4; ++i) {
      const int idx = t + 256 * i, kk = idx >> 2, esub = idx & 3;
      *(uint4*)&csh[0][esub][kk][0] = cpre[i];
    }
#pragma unroll
    for (int i = 0; i < 2; ++i) {
      const int idx = t + 256 * i, row = idx >> 3, e4 = idx & 7;
      *(half4v*)&xsh[0][e4 >> 1][row][(e4 & 1) * 4] = cvt4_f16(xpre[i]);
    }
  }
  __syncthreads();

  for (int g = 0; g < GTOT; ++g) {
    const int cur = g & 1;
    const int p = g >> 5;

    if ((g & 31) == 0) {
      if (g) {  // argmin update for pass p-1 (acc complete, snrm staged)
        const int kbaseU = (p - 1) * NKP;
#pragma unroll
        for (int kt = 0; kt < 2; ++kt) {
          const int kmb = w * 64 + kt * 32 + 4 * lhi;
#pragma unroll
          for (int r = 0; r < 16; ++r) {
            const int km = kmb + (r & 3) + 8 * (r >> 2);
            const float nk = snrm[km];
            const int kg = kbaseU + km;
#pragma unroll
            for (int nt = 0; nt < 2; ++nt) {
              const float d = fmaf(-2.0f, acc[kt][nt][r], nk);
              if (d < best[nt]) { best2[nt] = best[nt]; best[nt] = d; bidx[nt] = kg; }
              else best2[nt] = fminf(best2[nt], d);
            }
          }
        }
      }
#pragma unroll
      for (int kt = 0; kt < 2; ++kt)
#pragma unroll
        for (int nt = 0; nt < 2; ++nt)
#pragma unroll
          for (int i = 0; i < 16; ++i) acc[kt][nt][i] = 0.f;
    }

    // Prefetch chunk g+1 into registers (latency hidden under MFMA below).
    if (g + 1 < GTOT) {
      const int p1 = (g + 1) >> 5, ec1 = (g + 1) & 31;
      const int kbase1 = p1 * NKP, ebase1 = ec1 * KE;
#pragma unroll
      for (int i = 0; i < 4; ++i) {
        const int idx = t + 256 * i, kk = idx >> 2, esub = idx & 3;
        cpre[i] = *(const uint4*)(cf16 + (size_t)(kbase1 + kk) * DIM + ebase1 + esub * 8);
      }
#pragma unroll
      for (int i = 0; i < 2; ++i) {
        const int idx = t + 256 * i, row = idx >> 3, e4 = idx & 7;
        xpre[i] = *(const float4*)(x + (row0 + row) * DIM + ebase1 + 4 * e4);
      }
    }

    // Stage this pass's norms once (consumed 31 chunks later; barriers between).
    if ((g & 31) == 1) snrm[t] = nrm_g[p * NKP + t];

    // MFMA on buf[cur].
#pragma unroll
    for (int es = 0; es < 2; ++es) {
      const int esub = es * 2 + lhi;
      half8v A[2], B[2];
#pragma unroll
      for (int kt = 0; kt < 2; ++kt)
        A[kt] = *(const half8v*)&csh[cur][esub][w * 64 + kt * 32 + l31][0];
#pragma unroll
      for (int nt = 0; nt < 2; ++nt)
        B[nt] = *(const half8v*)&xsh[cur][esub][nt * 32 + l31][0];
#pragma unroll
      for (int kt = 0; kt < 2; ++kt)
#pragma unroll
        for (int nt = 0; nt < 2; ++nt)
          acc[kt][nt] = __builtin_amdgcn_mfma_f32_32x32x16_f16(
              A[kt], B[nt], acc[kt][nt], 0, 0, 0);
    }

    // Convert + write chunk g+1 into the other buffer.
    if (g + 1 < GTOT) {
      const int nb = cur ^ 1;
#pragma unroll
      for (int i = 0; i < 4; ++i) {
        const int idx = t + 256 * i, kk = idx >> 2, esub = idx & 3;
        *(uint4*)&csh[nb][esub][kk][0] = cpre[i];
      }
#pragma unroll
      for (int i = 0; i < 2; ++i) {
        const int idx = t + 256 * i, row = idx >> 3, e4 = idx & 7;
        *(half4v*)&xsh[nb][e4 >> 1][row][(e4 & 1) * 4] = cvt4_f16(xpre[i]);
      }
    }
    __syncthreads();
  }

  // Final argmin update (pass 7).
  {
    const int kbaseU = (NPASS - 1) * NKP;
#pragma unroll
    for (int kt = 0; kt < 2; ++kt) {
      const int kmb = w * 64 + kt * 32 + 4 * lhi;
#pragma unroll
      for (int r = 0; r < 16; ++r) {
        const int km = kmb + (r & 3) + 8 * (r >> 2);
        const float nk = snrm[km];
        const int kg = kbaseU + km;
#pragma unroll
        for (int nt = 0; nt < 2; ++nt) {
          const float d = fmaf(-2.0f, acc[kt][nt][r], nk);
          if (d < best[nt]) { best2[nt] = best[nt]; best[nt] = d; bidx[nt] = kg; }
          else best2[nt] = fminf(best2[nt], d);
        }
      }
    }
  }

  // Merge lane halves (l, l^32), then per-wave row candidates (R5-validated).
#pragma unroll
  for (int nt = 0; nt < 2; ++nt) {
    float b = best[nt], b2 = best2[nt];
    int bi = bidx[nt];
    const float ob  = __shfl_xor(b, 32, 64);
    const float ob2 = __shfl_xor(b2, 32, 64);
    const int   obi = __shfl_xor(bi, 32, 64);
    const float nb2 = fminf(fminf(b2, ob2), fmaxf(b, ob));
    if (ob < b || (ob == b && obi < bi)) { b = ob; bi = obi; }
    if (lhi == 0) {
      const int row = nt * 32 + l31;
      sbest[row][w] = b; sbest2[row][w] = nb2; sbidx[row][w] = bi;
    }
  }
  __syncthreads();

  if (t < MROWS) {
    float b = sbest[t][0], b2 = sbest2[t][0];
    int bi = sbidx[t][0];
#pragma unroll
    for (int ww = 1; ww < 4; ++ww) {
      const float cb = sbest[t][ww], cb2 = sbest2[t][ww];
      const int cbi = sbidx[t][ww];
      const float nb2 = fminf(fminf(b2, cb2), fmaxf(b, cb));
      if (cb < b || (cb == b && cbi < bi)) { b = cb; bi = cbi; }
      b2 = nb2;
    }
    sres[t] = bi;
    sflag[t] = (b2 - b < TAU) ? 1 : 0;
  }
  __syncthreads();

  // Exact fp32 rescore of flagged rows (~1-2 per block), R5-validated.
  float* xrow = (float*)&csh[0][0][0][0];  // 4 KB fp32 scratch
  for (int r = 0; r < MROWS; ++r) {
    if (sflag[r]) {
      __syncthreads();
      for (int i = t; i < DIM / 4; i += 256)
        ((float4*)xrow)[i] = *(const float4*)(x + (row0 + r) * DIM + 4 * i);
      __syncthreads();
      float bd = INFINITY; int bk = NCENT;
      for (int i = 0; i < NCENT / 256; ++i) {
        const int k = t + 256 * i;
        const float4* crow = (const float4*)(cent + (size_t)k * DIM);
        float a0 = 0.f, a1 = 0.f, a2 = 0.f, a3 = 0.f;
        float n0 = 0.f, n1 = 0.f, n2 = 0.f, n3 = 0.f;
#pragma unroll 8
        for (int j = 0; j < DIM / 4; ++j) {
          const float4 cv = crow[j];
          const float4 xv = ((const float4*)xrow)[j];
          a0 = fmaf(cv.x, xv.x, a0); n0 = fmaf(cv.x, cv.x, n0);
          a1 = fmaf(cv.y, xv.y, a1); n1 = fmaf(cv.y, cv.y, n1);
          a2 = fmaf(cv.z, xv.z, a2); n2 = fmaf(cv.z, cv.z, n2);
          a3 = fmaf(cv.w, xv.w, a3); n3 = fmaf(cv.w, cv.w, n3);
        }
        const float d = fmaf(-2.f, (a0 + a1) + (a2 + a3), (n0 + n1) + (n2 + n3));
        if (d < bd || (d == bd && k < bk)) { bd = d; bk = k; }
      }
#pragma unroll
      for (int off = 32; off > 0; off >>= 1) {
        const float od = __shfl_down(bd, off, 64);
        const int   ok = __shfl_down(bk, off, 64);
        if (od < bd || (od == bd && ok < bk)) { bd = od; bk = ok; }
      }
      if (lane == 0) { p2d[w] = bd; p2k[w] = bk; }
      __syncthreads();
      if (t == 0) {
        float fd = p2d[0]; int fk = p2k[0];
#pragma unroll
        for (int ww = 1; ww < 4; ++ww)
          if (p2d[ww] < fd || (p2d[ww] == fd && p2k[ww] < fk)) { fd = p2d[ww]; fk = p2k[ww]; }
        sres[r] = fk;
      }
      __syncthreads();
    }
  }
  __syncthreads();

  if (t < MROWS) out[row0 + t] = sres[t];
}

// ---------- Fallback (R5 kernel, validated): used only if ws too small ------
__device__ __forceinline__ void split4_f16(const float4 v, half4v& h, half4v& l) {
  const float f[4] = {v.x, v.y, v.z, v.w};
#pragma unroll
  for (int c = 0; c < 4; ++c) {
    const _Float16 hh = (_Float16)f[c];
    h[c] = hh;
    l[c] = (_Float16)(f[c] - (float)hh);
  }
}

__global__ void __launch_bounds__(256, 2) kmeans_mfma_fb(
    const float* __restrict__ x, const float* __restrict__ cent,
    int* __restrict__ out) {
  __shared__ __align__(16) _Float16 cs[2][4][CS_KK][8];
  __shared__ __align__(16) _Float16 xs[2][4][XS_KK][8];
  __shared__ float nrm[NKP];
  __shared__ float sbest[MROWS][4];
  __shared__ float sbest2[MROWS][4];
  __shared__ int   sbidx[MROWS][4];
  __shared__ int   sres[MROWS];
  __shared__ int   sflag[MROWS];
  __shared__ float p2d[4];
  __shared__ int   p2k[4];

  const int t = threadIdx.x, lane = t & 63, w = t >> 6;
  const int l31 = lane & 31, lhi = lane >> 5;
  const size_t row0 = (size_t)blockIdx.x * MROWS;
  float best[2] = {INFINITY, INFINITY}, best2[2] = {INFINITY, INFINITY};
  int bidx[2] = {0, 0};

  for (int p = 0; p < NPASS; ++p) {
    const int kbase = p * NKP;
    floatx16 acc[2][2] = {};
    float nacc[8] = {};
    for (int ec = 0; ec < NCHUNK; ++ec) {
      const int ebase = ec * KE;
      __syncthreads();
#pragma unroll
      for (int i = 0; i < 2; ++i) {
        const int idx = t + 256 * i, row = idx >> 3, e4 = idx & 7;
        const float4 v = *(const float4*)(x + (row0 + row) * DIM + ebase + 4 * e4);
        half4v h, l; split4_f16(v, h, l);
        *(half4v*)&xs[0][e4 >> 1][row][(e4 & 1) * 4] = h;
        *(half4v*)&xs[1][e4 >> 1][row][(e4 & 1) * 4] = l;
      }
#pragma unroll
      for (int i = 0; i < 8; ++i) {
        const int idx = t + 256 * i, kk = idx >> 3, e4 = idx & 7;
        const float4 v = *(const float4*)(cent + (size_t)(kbase + kk) * DIM + ebase + 4 * e4);
        nacc[i] = fmaf(v.x, v.x, nacc[i]); nacc[i] = fmaf(v.y, v.y, nacc[i]);
        nacc[i] = fmaf(v.z, v.z, nacc[i]); nacc[i] = fmaf(v.w, v.w, nacc[i]);
        half4v h, l; split4_f16(v, h, l);
        *(half4v*)&cs[0][e4 >> 1][kk][(e4 & 1) * 4] = h;
        *(half4v*)&cs[1][e4 >> 1][kk][(e4 & 1) * 4] = l;
      }
      __syncthreads();
#pragma unroll
      for (int es = 0; es < 2; ++es) {
        const int esub = es * 2 + lhi;
        half8v Ah[2], Al[2], Bh[2], Bl[2];
#pragma unroll
        for (int kt = 0; kt < 2; ++kt) {
          const int kk = w * 64 + kt * 32 + l31;
          Ah[kt] = *(const half8v*)&cs[0][esub][kk][0];
          Al[kt] = *(const half8v*)&cs[1][esub][kk][0];
        }
#pragma unroll
        for (int nt = 0; nt < 2; ++nt) {
          const int rr = nt * 32 + l31;
          Bh[nt] = *(const half8v*)&xs[0][esub][rr][0];
          Bl[nt] = *(const half8v*)&xs[1][esub][rr][0];
        }
#pragma unroll
        for (int kt = 0; kt < 2; ++kt)
#pragma unroll
          for (int nt = 0; nt < 2; ++nt) {
            acc[kt][nt] = __builtin_amdgcn_mfma_f32_32x32x16_f16(Ah[kt], Bh[nt], acc[kt][nt], 0, 0, 0);
            acc[kt][nt] = __builtin_amdgcn_mfma_f32_32x32x16_f16(Ah[kt], Bl[nt], acc[kt][nt], 0, 0, 0);
            acc[kt][nt] = __builtin_amdgcn_mfma_f32_32x32x16_f16(Al[kt], Bh[nt], acc[kt][nt], 0, 0, 0);
          }
      }
    }
#pragma unroll
    for (int i = 0; i < 8; ++i) {
      float n = nacc[i];
      n += __shfl_xor(n, 1, 64); n += __shfl_xor(n, 2, 64); n += __shfl_xor(n, 4, 64);
      if ((t & 7) == 0) nrm[(t >> 3) + 32 * i] = n;
    }
    __syncthreads();
#pragma unroll
    for (int kt = 0; kt < 2; ++kt) {
      const int kmb = w * 64 + kt * 32 + 4 * lhi;
#pragma unroll
      for (int r = 0; r < 16; ++r) {
        const int km = kmb + (r & 3) + 8 * (r >> 2);
        const float nk = nrm[km];
        const int kg = kbase + km;
#pragma unroll
        for (int nt = 0; nt < 2; ++nt) {
          const float d = fmaf(-2.0f, acc[kt][nt][r], nk);
          if (d < best[nt]) { best2[nt] = best[nt]; best[nt] = d; bidx[nt] = kg; }
          else best2[nt] = fminf(best2[nt], d);
        }
      }
    }
  }
#pragma unroll
  for (int nt = 0; nt < 2; ++nt) {
    float b = best[nt], b2 = best2[nt];
    int bi = bidx[nt];
    const float ob = __shfl_xor(b, 32, 64), ob2 = __shfl_xor(b2, 32, 64);
    const int obi = __shfl_xor(bi, 32, 64);
    const float nb2 = fminf(fminf(b2, ob2), fmaxf(b, ob));
    if (ob < b || (ob == b && obi < bi)) { b = ob; bi = obi; }
    if (lhi == 0) { const int row = nt * 32 + l31; sbest[row][w] = b; sbest2[row][w] = nb2; sbidx[row][w] = bi; }
  }
  __syncthreads();
  if (t < MROWS) {
    float b = sbest[t][0], b2 = sbest2[t][0];
    int bi = sbidx[t][0];
#pragma unroll
    for (int ww = 1; ww < 4; ++ww) {
      const float cb = sbest[t][ww], cb2 = sbest2[t][ww];
      const int cbi = sbidx[t][ww];
      const float nb2 = fminf(fminf(b2, cb2), fmaxf(b, cb));
      if (cb < b || (cb == b && cbi < bi)) { b = cb; bi = cbi; }
      b2 = nb2;
    }
    sres[t] = bi;
    sflag[t] = (b2 - b < TAU) ? 1 : 0;
  }
  __syncthreads();
  float* xrow = (float*)&xs[0][0][0][0];
  for (int r = 0; r < MROWS; ++r) {
    if (sflag[r]) {
      __syncthreads();
      for (int i = t; i < DIM / 4; i += 256)
        ((float4*)xrow)[i] = *(const float4*)(x + (row0 + r) * DIM + 4 * i);
      __syncthreads();
      float bd = INFINITY; int bk = NCENT;
      for (int i = 0; i < NCENT / 256; ++i) {
        const int k = t + 256 * i;
        const float4* crow = (const float4*)(cent + (size_t)k * DIM);
        float a0 = 0.f, a1 = 0.f, a2 = 0.f, a3 = 0.f, n0 = 0.f, n1 = 0.f, n2 = 0.f, n3 = 0.f;
#pragma unroll 8
        for (int j = 0; j < DIM / 4; ++j) {
          const float4 cv = crow[j]; const float4 xv = ((const float4*)xrow)[j];
          a0 = fmaf(cv.x, xv.x, a0); n0 = fmaf(cv.x, cv.x, n0);
          a1 = fmaf(cv.y, xv.y, a1); n1 = fmaf(cv.y, cv.y, n1);
          a2 = fmaf(cv.z, xv.z, a2); n2 = fmaf(cv.z, cv.z, n2);
          a3 = fmaf(cv.w, xv.w, a3); n3 = fmaf(cv.w, cv.w, n3);
        }
        const float d = fmaf(-2.f, (a0 + a1) + (a2 + a3), (n0 + n1) + (n2 + n3));
        if (d < bd || (d == bd && k < bk)) { bd = d; bk = k; }
      }
#pragma unroll
      for (int off = 32; off > 0; off >>= 1) {
        const float od = __shfl_down(bd, off, 64);
        const int ok = __shfl_down(bk, off, 64);
        if (od < bd || (od == bd && ok < bk)) { bd = od; bk = ok; }
      }
      if (lane == 0) { p2d[w] = bd; p2k[w] = bk; }
      __syncthreads();
      if (t == 0) {
        float fd = p2d[0]; int fk = p2k[0];
#pragma unroll
        for (int ww = 1; ww < 4; ++ww)
          if (p2d[ww] < fd || (p2d[ww] == fd && p2k[ww] < fk)) { fd = p2d[ww]; fk = p2k[ww]; }
        sres[r] = fk;
      }
      __syncthreads();
    }
  }
  __syncthreads();
  if (t < MROWS) out[row0 + t] = sres[t];
}

extern "C" void kernel_launch(void* const* d_in, const int* in_sizes, int n_in,
                              void* d_out, int out_size, void* d_ws, size_t ws_size,
                              hipStream_t stream) {
  const float* x    = (const float*)d_in[0];   // [16,2000,1024] fp32
  const float* cent = (const float*)d_in[1];   // [2048,1024] fp32
  int* out = (int*)d_out;                      // 32000 int32 indices

  const size_t CF16_BYTES = (size_t)NCENT * DIM * sizeof(_Float16);  // 4 MiB
  const size_t NEED = CF16_BYTES + (size_t)NCENT * sizeof(float);

  if (ws_size >= NEED) {
    _Float16* cf16 = (_Float16*)d_ws;
    float* nrm = (float*)((char*)d_ws + CF16_BYTES);
    hipLaunchKernelGGL(convert_c_kernel, dim3(NCENT), dim3(256), 0, stream,
                       cent, cf16, nrm);
    hipLaunchKernelGGL(kmeans_mfma_f16, dim3(N_ROWS / MROWS), dim3(256), 0,
                       stream, x, cf16, nrm, cent, out);
  } else {
    hipLaunchKernelGGL(kmeans_mfma_fb, dim3(N_ROWS / MROWS), dim3(256), 0,
                       stream, x, cent, out);
  }
}

// Round 8
// 2121.280 us; speedup vs baseline: 1.1441x; 1.1441x over previous
//
#include <hip/hip_runtime.h>
#include <math.h>

// Problem constants (B=16, T=2000, E=1024, K=2048)
#define N_ROWS 32000
#define DIM    1024
#define NCENT  2048
#define MROWS  64            // x rows per block
#define NKP    256           // centroids per k-pass
#define KE     32            // e per staged chunk
#define NPASS  (NCENT / NKP) // 8
#define NCHUNK (DIM / KE)    // 32
#define GTOT   (NPASS * NCHUNK) // 256 chunks of 16 KB f16
#define TAU    0.3f          // rescore margin (~13 sigma of f16 dot error)

typedef _Float16 half4v __attribute__((ext_vector_type(4)));
typedef _Float16 half8v __attribute__((ext_vector_type(8)));
typedef float    floatx16 __attribute__((ext_vector_type(16)));

__device__ __forceinline__ half4v cvt4_f16(const float4 v) {
  half4v h;
  h[0] = (_Float16)v.x; h[1] = (_Float16)v.y;
  h[2] = (_Float16)v.z; h[3] = (_Float16)v.w;
  return h;
}

// ---------- Kernel A: C fp32 -> f16, chunk-major transpose + fp32 norms -----
// cf16t layout: [g=(p*32+ec)][esub][kk][j] (16 KB per g) — the exact LDS image
// kernel B DMA-copies. k = p*256+kk, e = ec*32 + esub*8 + j.
__global__ void __launch_bounds__(256) convert_c_kernel(
    const float* __restrict__ cent, _Float16* __restrict__ cf16t,
    float* __restrict__ nrm) {
  const int k = blockIdx.x;         // 0..2047
  const int t = threadIdx.x;        // 0..255
  const int p = k >> 8, kk = k & 255;
  const float4 v = ((const float4*)(cent + (size_t)k * DIM))[t];  // e = 4t
  const int e = 4 * t;
  const int ec = e >> 5, esub = (e >> 3) & 3, eo = e & 7;  // eo in {0,4}
  float n = v.x * v.x + v.y * v.y + v.z * v.z + v.w * v.w;
  *(half4v*)(cf16t +
             ((((size_t)(p * 32 + ec) * 4 + esub) * 256 + kk) * 8 + eo)) =
      cvt4_f16(v);
  __shared__ float red[4];
#pragma unroll
  for (int off = 32; off > 0; off >>= 1) n += __shfl_down(n, off, 64);
  if ((t & 63) == 0) red[t >> 6] = n;
  __syncthreads();
  if (t == 0) nrm[k] = red[0] + red[1] + red[2] + red[3];
}

// ---------- Kernel B: f16 MFMA sweep (DMA-staged C) + fp32 rescue ----------
// R5 nested structure (acc scoped per pass -> no spill). Double-buffered LDS,
// 1 barrier/chunk; C staged via global_load_lds width=16 (wave-uniform base +
// lane*16 semantics; cf16t is pre-transposed so reads are fully contiguous).
// mfma_f32_32x32x16_f16 layouts validated in R5.
__global__ void __launch_bounds__(256, 2) kmeans_mfma_f16(
    const float* __restrict__ x, const _Float16* __restrict__ cf16t,
    const float* __restrict__ nrm_g, const float* __restrict__ cent,
    int* __restrict__ out) {
  __shared__ __align__(16) _Float16 csh[2][4][NKP][8];   // 2 x 16 KB
  __shared__ __align__(16) _Float16 xsh[2][4][MROWS][8]; // 2 x 4 KB
  __shared__ float snrm[NKP];
  __shared__ float sbest[MROWS][4];
  __shared__ float sbest2[MROWS][4];
  __shared__ int   sbidx[MROWS][4];
  __shared__ int   sres[MROWS];
  __shared__ int   sflag[MROWS];
  __shared__ float p2d[4];
  __shared__ int   p2k[4];

  const int t    = threadIdx.x;
  const int lane = t & 63;
  const int w    = t >> 6;
  const int l31  = lane & 31;
  const int lhi  = lane >> 5;
  const size_t row0 = (size_t)blockIdx.x * MROWS;
  const int xrow = t >> 2, xesub = t & 3;        // x staging ownership
  const int xrowS = xrow ^ (xesub << 1);         // XOR-swizzle: conflict-free writes

  float best[2]  = {INFINITY, INFINITY};
  float best2[2] = {INFINITY, INFINITY};
  int   bidx[2]  = {0, 0};

  // stage chunk g into buffer buf: C via 4x global_load_lds dwordx4, x via cvt.
  auto stage = [&](int g, int buf) {
    const _Float16* src = cf16t + (size_t)g * (NKP * KE);  // 16 KB block
    _Float16* ldsb = &csh[buf][0][0][0];
#pragma unroll
    for (int i = 0; i < 4; ++i) {
      const int sb = (i * 4 + w) * 64;  // wave-uniform slot base
      __builtin_amdgcn_global_load_lds(
          (const __attribute__((address_space(1))) void*)(src + (size_t)(sb + lane) * 8),
          (__attribute__((address_space(3))) void*)(ldsb + (size_t)sb * 8),
          16, 0, 0);
    }
    const int ebase = (g & (NCHUNK - 1)) * KE;
    const float* xp = x + (row0 + xrow) * DIM + ebase + xesub * 8;
    const float4 a = *(const float4*)xp;
    const float4 b = *(const float4*)(xp + 4);
    half8v h;
    h[0] = (_Float16)a.x; h[1] = (_Float16)a.y; h[2] = (_Float16)a.z; h[3] = (_Float16)a.w;
    h[4] = (_Float16)b.x; h[5] = (_Float16)b.y; h[6] = (_Float16)b.z; h[7] = (_Float16)b.w;
    *(half8v*)&xsh[buf][xesub][xrowS][0] = h;
  };

  stage(0, 0);
  __syncthreads();

  for (int p = 0; p < NPASS; ++p) {
    floatx16 acc[2][2] = {};   // [kt][nt] — scoped per pass (R7 spill lesson)
    snrm[t] = nrm_g[p * NKP + t];  // safe: barrier before (pass-end/prologue)

    for (int ec = 0; ec < NCHUNK; ++ec) {
      const int g = p * NCHUNK + ec;
      const int cur = g & 1;
      if (g + 1 < GTOT) stage(g + 1, cur ^ 1);

#pragma unroll
      for (int es = 0; es < 2; ++es) {
        const int esub = es * 2 + lhi;
        half8v A[2], B[2];
#pragma unroll
        for (int kt = 0; kt < 2; ++kt)
          A[kt] = *(const half8v*)&csh[cur][esub][w * 64 + kt * 32 + l31][0];
#pragma unroll
        for (int nt = 0; nt < 2; ++nt)
          B[nt] = *(const half8v*)&xsh[cur][esub][(nt * 32 + l31) ^ (esub << 1)][0];
#pragma unroll
        for (int kt = 0; kt < 2; ++kt)
#pragma unroll
          for (int nt = 0; nt < 2; ++nt)
            acc[kt][nt] = __builtin_amdgcn_mfma_f32_32x32x16_f16(
                A[kt], B[nt], acc[kt][nt], 0, 0, 0);
      }
      __syncthreads();  // drains DMA (vmcnt) + orders LDS for next chunk
    }

    // Argmin update for pass p (R5-validated mapping).
    const int kbase = p * NKP;
#pragma unroll
    for (int kt = 0; kt < 2; ++kt) {
      const int kmb = w * 64 + kt * 32 + 4 * lhi;
#pragma unroll
      for (int r = 0; r < 16; ++r) {
        const int km = kmb + (r & 3) + 8 * (r >> 2);
        const float nk = snrm[km];
        const int kg = kbase + km;
#pragma unroll
        for (int nt = 0; nt < 2; ++nt) {
          const float d = fmaf(-2.0f, acc[kt][nt][r], nk);
          if (d < best[nt]) { best2[nt] = best[nt]; best[nt] = d; bidx[nt] = kg; }
          else best2[nt] = fminf(best2[nt], d);
        }
      }
    }
    __syncthreads();  // protect snrm before next pass overwrites it
  }

  // Merge lane halves (l, l^32), per-wave candidates (R5-validated).
#pragma unroll
  for (int nt = 0; nt < 2; ++nt) {
    float b = best[nt], b2 = best2[nt];
    int bi = bidx[nt];
    const float ob  = __shfl_xor(b, 32, 64);
    const float ob2 = __shfl_xor(b2, 32, 64);
    const int   obi = __shfl_xor(bi, 32, 64);
    const float nb2 = fminf(fminf(b2, ob2), fmaxf(b, ob));
    if (ob < b || (ob == b && obi < bi)) { b = ob; bi = obi; }
    if (lhi == 0) {
      const int row = nt * 32 + l31;
      sbest[row][w] = b; sbest2[row][w] = nb2; sbidx[row][w] = bi;
    }
  }
  __syncthreads();

  if (t < MROWS) {
    float b = sbest[t][0], b2 = sbest2[t][0];
    int bi = sbidx[t][0];
#pragma unroll
    for (int ww = 1; ww < 4; ++ww) {
      const float cb = sbest[t][ww], cb2 = sbest2[t][ww];
      const int cbi = sbidx[t][ww];
      const float nb2 = fminf(fminf(b2, cb2), fmaxf(b, cb));
      if (cb < b || (cb == b && cbi < bi)) { b = cb; bi = cbi; }
      b2 = nb2;
    }
    sres[t] = bi;
    sflag[t] = (b2 - b < TAU) ? 1 : 0;
  }
  __syncthreads();

  // Exact fp32 rescore of flagged rows (~1-2 per block), R5-validated.
  float* xrow_s = (float*)&csh[0][0][0][0];  // 4 KB fp32 scratch
  for (int r = 0; r < MROWS; ++r) {
    if (sflag[r]) {
      __syncthreads();
      for (int i = t; i < DIM / 4; i += 256)
        ((float4*)xrow_s)[i] = *(const float4*)(x + (row0 + r) * DIM + 4 * i);
      __syncthreads();
      float bd = INFINITY; int bk = NCENT;
      for (int i = 0; i < NCENT / 256; ++i) {
        const int k = t + 256 * i;
        const float4* crow = (const float4*)(cent + (size_t)k * DIM);
        float a0 = 0.f, a1 = 0.f, a2 = 0.f, a3 = 0.f;
        float n0 = 0.f, n1 = 0.f, n2 = 0.f, n3 = 0.f;
#pragma unroll 8
        for (int j = 0; j < DIM / 4; ++j) {
          const float4 cv = crow[j];
          const float4 xv = ((const float4*)xrow_s)[j];
          a0 = fmaf(cv.x, xv.x, a0); n0 = fmaf(cv.x, cv.x, n0);
          a1 = fmaf(cv.y, xv.y, a1); n1 = fmaf(cv.y, cv.y, n1);
          a2 = fmaf(cv.z, xv.z, a2); n2 = fmaf(cv.z, cv.z, n2);
          a3 = fmaf(cv.w, xv.w, a3); n3 = fmaf(cv.w, cv.w, n3);
        }
        const float d = fmaf(-2.f, (a0 + a1) + (a2 + a3), (n0 + n1) + (n2 + n3));
        if (d < bd || (d == bd && k < bk)) { bd = d; bk = k; }
      }
#pragma unroll
      for (int off = 32; off > 0; off >>= 1) {
        const float od = __shfl_down(bd, off, 64);
        const int   ok = __shfl_down(bk, off, 64);
        if (od < bd || (od == bd && ok < bk)) { bd = od; bk = ok; }
      }
      if (lane == 0) { p2d[w] = bd; p2k[w] = bk; }
      __syncthreads();
      if (t == 0) {
        float fd = p2d[0]; int fk = p2k[0];
#pragma unroll
        for (int ww = 1; ww < 4; ++ww)
          if (p2d[ww] < fd || (p2d[ww] == fd && p2k[ww] < fk)) { fd = p2d[ww]; fk = p2k[ww]; }
        sres[r] = fk;
      }
      __syncthreads();
    }
  }
  __syncthreads();

  if (t < MROWS) out[row0 + t] = sres[t];
}

// ---------- Fallback (R5 kernel, validated): used only if ws too small ------
__device__ __forceinline__ void split4_f16(const float4 v, half4v& h, half4v& l) {
  const float f[4] = {v.x, v.y, v.z, v.w};
#pragma unroll
  for (int c = 0; c < 4; ++c) {
    const _Float16 hh = (_Float16)f[c];
    h[c] = hh;
    l[c] = (_Float16)(f[c] - (float)hh);
  }
}

#define CS_KK 257
#define XS_KK 65

__global__ void __launch_bounds__(256, 2) kmeans_mfma_fb(
    const float* __restrict__ x, const float* __restrict__ cent,
    int* __restrict__ out) {
  __shared__ __align__(16) _Float16 cs[2][4][CS_KK][8];
  __shared__ __align__(16) _Float16 xs[2][4][XS_KK][8];
  __shared__ float nrm[NKP];
  __shared__ float sbest[MROWS][4];
  __shared__ float sbest2[MROWS][4];
  __shared__ int   sbidx[MROWS][4];
  __shared__ int   sres[MROWS];
  __shared__ int   sflag[MROWS];
  __shared__ float p2d[4];
  __shared__ int   p2k[4];

  const int t = threadIdx.x, lane = t & 63, w = t >> 6;
  const int l31 = lane & 31, lhi = lane >> 5;
  const size_t row0 = (size_t)blockIdx.x * MROWS;
  float best[2] = {INFINITY, INFINITY}, best2[2] = {INFINITY, INFINITY};
  int bidx[2] = {0, 0};

  for (int p = 0; p < NPASS; ++p) {
    const int kbase = p * NKP;
    floatx16 acc[2][2] = {};
    float nacc[8] = {};
    for (int ec = 0; ec < NCHUNK; ++ec) {
      const int ebase = ec * KE;
      __syncthreads();
#pragma unroll
      for (int i = 0; i < 2; ++i) {
        const int idx = t + 256 * i, row = idx >> 3, e4 = idx & 7;
        const float4 v = *(const float4*)(x + (row0 + row) * DIM + ebase + 4 * e4);
        half4v h, l; split4_f16(v, h, l);
        *(half4v*)&xs[0][e4 >> 1][row][(e4 & 1) * 4] = h;
        *(half4v*)&xs[1][e4 >> 1][row][(e4 & 1) * 4] = l;
      }
#pragma unroll
      for (int i = 0; i < 8; ++i) {
        const int idx = t + 256 * i, kk = idx >> 3, e4 = idx & 7;
        const float4 v = *(const float4*)(cent + (size_t)(kbase + kk) * DIM + ebase + 4 * e4);
        nacc[i] = fmaf(v.x, v.x, nacc[i]); nacc[i] = fmaf(v.y, v.y, nacc[i]);
        nacc[i] = fmaf(v.z, v.z, nacc[i]); nacc[i] = fmaf(v.w, v.w, nacc[i]);
        half4v h, l; split4_f16(v, h, l);
        *(half4v*)&cs[0][e4 >> 1][kk][(e4 & 1) * 4] = h;
        *(half4v*)&cs[1][e4 >> 1][kk][(e4 & 1) * 4] = l;
      }
      __syncthreads();
#pragma unroll
      for (int es = 0; es < 2; ++es) {
        const int esub = es * 2 + lhi;
        half8v Ah[2], Al[2], Bh[2], Bl[2];
#pragma unroll
        for (int kt = 0; kt < 2; ++kt) {
          const int kk = w * 64 + kt * 32 + l31;
          Ah[kt] = *(const half8v*)&cs[0][esub][kk][0];
          Al[kt] = *(const half8v*)&cs[1][esub][kk][0];
        }
#pragma unroll
        for (int nt = 0; nt < 2; ++nt) {
          const int rr = nt * 32 + l31;
          Bh[nt] = *(const half8v*)&xs[0][esub][rr][0];
          Bl[nt] = *(const half8v*)&xs[1][esub][rr][0];
        }
#pragma unroll
        for (int kt = 0; kt < 2; ++kt)
#pragma unroll
          for (int nt = 0; nt < 2; ++nt) {
            acc[kt][nt] = __builtin_amdgcn_mfma_f32_32x32x16_f16(Ah[kt], Bh[nt], acc[kt][nt], 0, 0, 0);
            acc[kt][nt] = __builtin_amdgcn_mfma_f32_32x32x16_f16(Ah[kt], Bl[nt], acc[kt][nt], 0, 0, 0);
            acc[kt][nt] = __builtin_amdgcn_mfma_f32_32x32x16_f16(Al[kt], Bh[nt], acc[kt][nt], 0, 0, 0);
          }
      }
    }
#pragma unroll
    for (int i = 0; i < 8; ++i) {
      float n = nacc[i];
      n += __shfl_xor(n, 1, 64); n += __shfl_xor(n, 2, 64); n += __shfl_xor(n, 4, 64);
      if ((t & 7) == 0) nrm[(t >> 3) + 32 * i] = n;
    }
    __syncthreads();
#pragma unroll
    for (int kt = 0; kt < 2; ++kt) {
      const int kmb = w * 64 + kt * 32 + 4 * lhi;
#pragma unroll
      for (int r = 0; r < 16; ++r) {
        const int km = kmb + (r & 3) + 8 * (r >> 2);
        const float nk = nrm[km];
        const int kg = kbase + km;
#pragma unroll
        for (int nt = 0; nt < 2; ++nt) {
          const float d = fmaf(-2.0f, acc[kt][nt][r], nk);
          if (d < best[nt]) { best2[nt] = best[nt]; best[nt] = d; bidx[nt] = kg; }
          else best2[nt] = fminf(best2[nt], d);
        }
      }
    }
  }
#pragma unroll
  for (int nt = 0; nt < 2; ++nt) {
    float b = best[nt], b2 = best2[nt];
    int bi = bidx[nt];
    const float ob = __shfl_xor(b, 32, 64), ob2 = __shfl_xor(b2, 32, 64);
    const int obi = __shfl_xor(bi, 32, 64);
    const float nb2 = fminf(fminf(b2, ob2), fmaxf(b, ob));
    if (ob < b || (ob == b && obi < bi)) { b = ob; bi = obi; }
    if (lhi == 0) { const int row = nt * 32 + l31; sbest[row][w] = b; sbest2[row][w] = nb2; sbidx[row][w] = bi; }
  }
  __syncthreads();
  if (t < MROWS) {
    float b = sbest[t][0], b2 = sbest2[t][0];
    int bi = sbidx[t][0];
#pragma unroll
    for (int ww = 1; ww < 4; ++ww) {
      const float cb = sbest[t][ww], cb2 = sbest2[t][ww];
      const int cbi = sbidx[t][ww];
      const float nb2 = fminf(fminf(b2, cb2), fmaxf(b, cb));
      if (cb < b || (cb == b && cbi < bi)) { b = cb; bi = cbi; }
      b2 = nb2;
    }
    sres[t] = bi;
    sflag[t] = (b2 - b < TAU) ? 1 : 0;
  }
  __syncthreads();
  float* xrow = (float*)&xs[0][0][0][0];
  for (int r = 0; r < MROWS; ++r) {
    if (sflag[r]) {
      __syncthreads();
      for (int i = t; i < DIM / 4; i += 256)
        ((float4*)xrow)[i] = *(const float4*)(x + (row0 + r) * DIM + 4 * i);
      __syncthreads();
      float bd = INFINITY; int bk = NCENT;
      for (int i = 0; i < NCENT / 256; ++i) {
        const int k = t + 256 * i;
        const float4* crow = (const float4*)(cent + (size_t)k * DIM);
        float a0 = 0.f, a1 = 0.f, a2 = 0.f, a3 = 0.f, n0 = 0.f, n1 = 0.f, n2 = 0.f, n3 = 0.f;
#pragma unroll 8
        for (int j = 0; j < DIM / 4; ++j) {
          const float4 cv = crow[j]; const float4 xv = ((const float4*)xrow)[j];
          a0 = fmaf(cv.x, xv.x, a0); n0 = fmaf(cv.x, cv.x, n0);
          a1 = fmaf(cv.y, xv.y, a1); n1 = fmaf(cv.y, cv.y, n1);
          a2 = fmaf(cv.z, xv.z, a2); n2 = fmaf(cv.z, cv.z, n2);
          a3 = fmaf(cv.w, xv.w, a3); n3 = fmaf(cv.w, cv.w, n3);
        }
        const float d = fmaf(-2.f, (a0 + a1) + (a2 + a3), (n0 + n1) + (n2 + n3));
        if (d < bd || (d == bd && k < bk)) { bd = d; bk = k; }
      }
#pragma unroll
      for (int off = 32; off > 0; off >>= 1) {
        const float od = __shfl_down(bd, off, 64);
        const int ok = __shfl_down(bk, off, 64);
        if (od < bd || (od == bd && ok < bk)) { bd = od; bk = ok; }
      }
      if (lane == 0) { p2d[w] = bd; p2k[w] = bk; }
      __syncthreads();
      if (t == 0) {
        float fd = p2d[0]; int fk = p2k[0];
#pragma unroll
        for (int ww = 1; ww < 4; ++ww)
          if (p2d[ww] < fd || (p2d[ww] == fd && p2k[ww] < fk)) { fd = p2d[ww]; fk = p2k[ww]; }
        sres[r] = fk;
      }
      __syncthreads();
    }
  }
  __syncthreads();
  if (t < MROWS) out[row0 + t] = sres[t];
}

extern "C" void kernel_launch(void* const* d_in, const int* in_sizes, int n_in,
                              void* d_out, int out_size, void* d_ws, size_t ws_size,
                              hipStream_t stream) {
  const float* x    = (const float*)d_in[0];   // [16,2000,1024] fp32
  const float* cent = (const float*)d_in[1];   // [2048,1024] fp32
  int* out = (int*)d_out;                      // 32000 int32 indices

  const size_t CF16_BYTES = (size_t)NCENT * DIM * sizeof(_Float16);  // 4 MiB
  const size_t NEED = CF16_BYTES + (size_t)NCENT * sizeof(float);

  if (ws_size >= NEED) {
    _Float16* cf16t = (_Float16*)d_ws;
    float* nrm = (float*)((char*)d_ws + CF16_BYTES);
    hipLaunchKernelGGL(convert_c_kernel, dim3(NCENT), dim3(256), 0, stream,
                       cent, cf16t, nrm);
    hipLaunchKernelGGL(kmeans_mfma_f16, dim3(N_ROWS / MROWS), dim3(256), 0,
                       stream, x, cf16t, nrm, cent, out);
  } else {
    hipLaunchKernelGGL(kmeans_mfma_fb, dim3(N_ROWS / MROWS), dim3(256), 0,
                       stream, x, cent, out);
  }
}